// Round 14
// baseline (189.219 us; speedup 1.0000x reference)
//
#include <hip/hip_runtime.h>
#include <hip/hip_bf16.h>
#include <stdint.h>

#define N_NODES 10000
#define N_EDGES 160000
#define FEAT    256
#define NRELS   16
#define BM      64          // row tile
#define NCHUNK  32          // 16 rels x {fwd,bwd}; proj row chunk = rd in [0,32)
#define NTILES  157         // ceil(N_NODES/BM)
#define SELFY   5           // ceil(NTILES/NCHUNK) extra y-rows carry the self-loop tiles
#define KBYTES  512         // one A row = 256 bf16 = 512 B

typedef __attribute__((ext_vector_type(8))) short bf16x8;
typedef __attribute__((ext_vector_type(4))) float f32x4;

// async global->LDS, 16B per lane; dest = uniform base + lane*16 (HW)
#define GLL16(gsrc, ldst) \
    __builtin_amdgcn_global_load_lds( \
        (const __attribute__((address_space(1))) void*)(gsrc), \
        (__attribute__((address_space(3))) void*)(ldst), 16, 0, 0)

__device__ __forceinline__ unsigned short f2bf(float f) {
    union { float f; unsigned u; } v; v.f = f;
    unsigned u = v.u;
    u += 0x7FFFu + ((u >> 16) & 1u);   // round-to-nearest-even
    return (unsigned short)(u >> 16);
}
__device__ __forceinline__ float bf2f(unsigned short u) {
    union { unsigned u; float f; } v; v.u = ((unsigned)u) << 16;
    return v.f;
}

// ---- fused prep: fp32 -> bf16 feat conversion + degree counting ----
__global__ __launch_bounds__(256) void k_prep(const float4* __restrict__ src4,
                                              ushort4* __restrict__ dst4, int n4,
                                              const int* __restrict__ src,
                                              const int* __restrict__ dst,
                                              int* degd, int* degs) {
    int i = blockIdx.x * 256 + threadIdx.x;
    if (i < n4) {
        float4 v = src4[i];
        ushort4 r;
        r.x = f2bf(v.x); r.y = f2bf(v.y); r.z = f2bf(v.z); r.w = f2bf(v.w);
        dst4[i] = r;
    }
    if (i < N_EDGES) {
        atomicAdd(&degd[dst[i]], 1);
        atomicAdd(&degs[src[i]], 1);
    }
}

// ---- all weight transposes: z<16 Wf -> rd 2z, z<32 Wb -> rd 2z+1, z==32 lw -> lwt ----
__global__ __launch_bounds__(256) void k_wtall(const float* __restrict__ Wf,
                                               const float* __restrict__ Wb,
                                               const float* __restrict__ lw,
                                               unsigned short* __restrict__ wall,
                                               unsigned short* __restrict__ lwt) {
    __shared__ float tile[64][65];
    int z = blockIdx.z;
    const float* w;
    unsigned short* o;
    if (z < 16)      { w = Wf + (size_t)z * 65536;        o = wall + (size_t)(z * 2) * 65536; }
    else if (z < 32) { w = Wb + (size_t)(z - 16) * 65536; o = wall + (size_t)((z - 16) * 2 + 1) * 65536; }
    else             { w = lw;                            o = lwt; }
    int i0 = blockIdx.x * 64, o0 = blockIdx.y * 64;
    int t = threadIdx.x;
    int c = t & 63, q = t >> 6;
#pragma unroll
    for (int it = 0; it < 16; it++) {
        int i = it * 4 + q;
        tile[i][c] = w[(size_t)(i0 + i) * 256 + o0 + c];
    }
    __syncthreads();
#pragma unroll
    for (int it = 0; it < 16; it++) {
        int oo = it * 4 + q;
        o[(size_t)(o0 + oo) * 256 + i0 + c] = f2bf(tile[c][oo]);
    }
}

// ---- parallel segment allocation: block-level scan + atomic base (order-free CSR) ----
__global__ __launch_bounds__(256) void k_off(const int* __restrict__ degd,
                                             const int* __restrict__ degs,
                                             int* offf, int* offb,
                                             int* curf, int* curb,
                                             float* normf, float* normb,
                                             int* gcnt) {
    __shared__ int sf[256], sb[256];
    __shared__ int basef, baseb;
    int t = threadIdx.x;
    int n = blockIdx.x * 256 + t;
    int df = (n < N_NODES) ? degd[n] : 0;
    int db = (n < N_NODES) ? degs[n] : 0;
    sf[t] = df; sb[t] = db;
    __syncthreads();
    for (int d = 1; d < 256; d <<= 1) {
        int vf = (t >= d) ? sf[t - d] : 0;
        int vb = (t >= d) ? sb[t - d] : 0;
        __syncthreads();
        sf[t] += vf; sb[t] += vb;
        __syncthreads();
    }
    if (t == 255) {
        basef = atomicAdd(&gcnt[0], sf[255]);
        baseb = atomicAdd(&gcnt[1], sb[255]);
    }
    __syncthreads();
    if (n < N_NODES) {
        int ef = basef + sf[t] - df;     // exclusive prefix + block base
        int eb = baseb + sb[t] - db;
        offf[n] = ef; offb[n] = eb;
        curf[n] = ef; curb[n] = eb;
        normf[n] = df > 0 ? 1.f / (float)df : 0.f;
        normb[n] = db > 0 ? 1.f / (float)db : 0.f;
    }
}

// ---- CSR fill: store proj chunk index (node*32 + et*2 + dir) ----
__global__ __launch_bounds__(256) void k_fill(const int* __restrict__ et,
                                              const int* __restrict__ src,
                                              const int* __restrict__ dst,
                                              int* curf, int* curb,
                                              int* csrf, int* csrb) {
    int e = blockIdx.x * 256 + threadIdx.x;
    if (e < N_EDGES) {
        int s = src[e], d = dst[e], r = et[e];
        csrf[atomicAdd(&curf[d], 1)] = s * NCHUNK + r * 2;       // fwd: feat[src] @ Wf
        csrb[atomicAdd(&curb[s], 1)] = d * NCHUNK + r * 2 + 1;   // bwd: feat[dst] @ Wb
    }
}

// ---- dense projection (+ fused self loop on extra y-tiles) ----
// y <  NTILES: proj[n][rd][256] = feat @ W_rd  -- exact r5/r13 structure, but the
//              A-stage uses global_load_lds (async DMA) with pre-swizzled source.
// y >= NTILES: self tile st=(y-NTILES)*32+rd: out = 2*(feat@lw) + sbias (fp32 direct).
__global__ __launch_bounds__(256) void k_proj(const unsigned short* __restrict__ featb,
                                              const unsigned short* __restrict__ wall,
                                              const unsigned short* __restrict__ lwt,
                                              const float* __restrict__ sbias,
                                              unsigned short* __restrict__ proj,
                                              float* __restrict__ out) {
    __shared__ __align__(16) char lds[BM * KBYTES];   // 32 KB: A tile, reused for out-stage
    int rd = blockIdx.x;
    int y  = blockIdx.y;
    int t = threadIdx.x;
    int wave = t >> 6, lane = t & 63;
    int nb = wave * 64, lr = lane & 15, lg = lane >> 4;

    if (y >= NTILES) {
        // ---------------- fused self loop (whole-block branch, no barriers) ---------
        int st = (y - NTILES) * NCHUNK + rd;
        if (st >= NTILES) return;
        int m0 = st * BM;
        f32x4 acc[4][4] = {};
        for (int k0 = 0; k0 < FEAT; k0 += 32) {
            int kk = k0 + lg * 8;
            bf16x8 a[4], b[4];
            for (int mi = 0; mi < 4; mi++) {
                int row = m0 + mi * 16 + lr;
                if (row >= N_NODES) row = N_NODES - 1;
                a[mi] = *(const bf16x8*)(featb + row * FEAT + kk);
            }
            for (int ni = 0; ni < 4; ni++)
                b[ni] = *(const bf16x8*)(lwt + (nb + ni * 16 + lr) * FEAT + kk);
            for (int mi = 0; mi < 4; mi++)
                for (int ni = 0; ni < 4; ni++)
                    acc[mi][ni] = __builtin_amdgcn_mfma_f32_16x16x32_bf16(a[mi], b[ni], acc[mi][ni], 0, 0, 0);
        }
        for (int mi = 0; mi < 4; mi++) {
#pragma unroll
            for (int j = 0; j < 4; j++) {
                int row = m0 + mi * 16 + lg * 4 + j;
                if (row < N_NODES) {
                    for (int ni = 0; ni < 4; ni++) {
                        int col = nb + ni * 16 + lr;
                        out[(size_t)row * FEAT + col] = 2.0f * acc[mi][ni][j] + sbias[col];
                    }
                }
            }
        }
        return;
    }

    // ---------------- dense projection ----------------
    int m0 = y * BM;
    const unsigned short* wr = wall + (size_t)rd * 256 * FEAT;

    // async stage A tile [64][512B] swizzled: LDS[row*512 + kb] = feat[row][kb ^ sw(row)]
    // (XOR is an involution; k-loop reads LDS[row*512 + (kb ^ sw)] = feat[row][kb])
    {
        int rbase = 2 * wave;                 // 2 rows per wave per issue
        int rofs = lane >> 5;                 // 0/1: which row this lane feeds
        int within = (lane & 31) << 4;        // linear 16B chunk within the row
#pragma unroll
        for (int it = 0; it < 8; it++) {
            int row = it * 8 + rbase + rofs;
            int gr = m0 + row; if (gr > N_NODES - 1) gr = N_NODES - 1;
            const char* gsrc = (const char*)featb + (size_t)gr * KBYTES
                               + (within ^ ((row & 7) << 4));
            GLL16(gsrc, lds + (it * 8 + rbase) * KBYTES);
        }
    }
    __syncthreads();   // compiler drains vmcnt before barrier

    f32x4 acc[4][4] = {};
#pragma unroll 2
    for (int k0 = 0; k0 < FEAT; k0 += 32) {
        int kb = (k0 + lg * 8) * 2;
        bf16x8 a[4], b[4];
        for (int ni = 0; ni < 4; ni++)
            b[ni] = *(const bf16x8*)(wr + (nb + ni * 16 + lr) * FEAT + k0 + lg * 8);
        for (int mi = 0; mi < 4; mi++) {
            int row = mi * 16 + lr;
            a[mi] = *(const bf16x8*)(lds + row * KBYTES + (kb ^ ((row & 7) << 4)));
        }
        for (int mi = 0; mi < 4; mi++)
            for (int ni = 0; ni < 4; ni++)
                acc[mi][ni] = __builtin_amdgcn_mfma_f32_16x16x32_bf16(a[mi], b[ni], acc[mi][ni], 0, 0, 0);
    }
    __syncthreads();

    // out-stage: bf16 results into LDS [64][256] linear
    for (int mi = 0; mi < 4; mi++) {
#pragma unroll
        for (int j = 0; j < 4; j++) {
            int row = mi * 16 + lg * 4 + j;
            for (int ni = 0; ni < 4; ni++)
                *(unsigned short*)(lds + row * KBYTES + (nb + ni * 16 + lr) * 2) =
                    f2bf(acc[mi][ni][j]);
        }
    }
    __syncthreads();

    // coalesced global write: 16B/lane, 512B bursts per row
    {
        int rl = t >> 5;
        int kb = (t & 31) << 4;
#pragma unroll
        for (int it = 0; it < 8; it++) {
            int row = it * 8 + rl;
            int gr = m0 + row;
            if (gr < N_NODES)
                *(bf16x8*)(proj + ((size_t)gr * NCHUNK + rd) * FEAT + (kb >> 1)) =
                    *(const bf16x8*)(lds + row * KBYTES + kb);
        }
    }
}

// ---- pull reduce: one wave per node, two 32-lane halves; RMW out (self already there) ----
__global__ __launch_bounds__(256) void k_reduce(const unsigned short* __restrict__ proj,
                                                const int* __restrict__ csrf,
                                                const int* __restrict__ csrb,
                                                const int* __restrict__ offf,
                                                const int* __restrict__ offb,
                                                const int* __restrict__ degd,
                                                const int* __restrict__ degs,
                                                const float* __restrict__ normf,
                                                const float* __restrict__ normb,
                                                const float* __restrict__ biasf,
                                                const float* __restrict__ biasb,
                                                float* __restrict__ out) {
    int node = blockIdx.x * 4 + (threadIdx.x >> 6);
    if (node >= N_NODES) return;
    int lane = threadIdx.x & 63;
    int half = lane >> 5;            // 0: even edges, 1: odd edges
    int li = lane & 31;              // 16B segment within the 512B row

    float af[8] = {0,0,0,0,0,0,0,0};
    float ab[8] = {0,0,0,0,0,0,0,0};

    int b0 = offf[node], dfc = degd[node];
    int b1 = b0 + dfc;
#pragma unroll 8
    for (int s = b0 + half; s < b1; s += 2) {
        int c = csrf[s];
        bf16x8 m = *(const bf16x8*)(proj + (size_t)c * FEAT + li * 8);
#pragma unroll
        for (int k = 0; k < 8; k++) af[k] += bf2f((unsigned short)m[k]);
    }
    int c0 = offb[node], dbc = degs[node];
    int c1 = c0 + dbc;
#pragma unroll 8
    for (int s = c0 + half; s < c1; s += 2) {
        int c = csrb[s];
        bf16x8 m = *(const bf16x8*)(proj + (size_t)c * FEAT + li * 8);
#pragma unroll
        for (int k = 0; k < 8; k++) ab[k] += bf2f((unsigned short)m[k]);
    }

    float nf = normf[node], nbv = normb[node];
    float v[8];
#pragma unroll
    for (int k = 0; k < 8; k++) v[k] = nf * af[k] + nbv * ab[k];
#pragma unroll
    for (int k = 0; k < 8; k++) v[k] += __shfl_xor(v[k], 32);   // combine halves

    // lane updates 4 floats at col = li*8 + half*4 (coalesced 1KB per wave)
    int col = li * 8 + half * 4;
    float4 bfv = *(const float4*)(biasf + col);
    float4 bbv = *(const float4*)(biasb + col);
    float fb = (dfc > 0) ? 1.f : 0.f;
    float bb = (dbc > 0) ? 1.f : 0.f;
    float4 o = *(float4*)(out + (size_t)node * FEAT + col);
    int k0 = half * 4;
    o.x += v[k0 + 0] + fb * bfv.x + bb * bbv.x;
    o.y += v[k0 + 1] + fb * bfv.y + bb * bbv.y;
    o.z += v[k0 + 2] + fb * bfv.z + bb * bbv.z;
    o.w += v[k0 + 3] + fb * bfv.w + bb * bbv.w;
    *(float4*)(out + (size_t)node * FEAT + col) = o;
}

extern "C" void kernel_launch(void* const* d_in, const int* in_sizes, int n_in,
                              void* d_out, int out_size, void* d_ws, size_t ws_size,
                              hipStream_t stream) {
    const float* feat  = (const float*)d_in[0];
    const float* Wf    = (const float*)d_in[1];
    const float* Wb    = (const float*)d_in[2];
    const float* lw    = (const float*)d_in[3];
    const float* fbias = (const float*)d_in[4];
    const float* bbias = (const float*)d_in[5];
    const float* sbias = (const float*)d_in[6];
    const int*   src   = (const int*)d_in[7];
    const int*   dst   = (const int*)d_in[8];
    const int*   et    = (const int*)d_in[9];
    float* out = (float*)d_out;

    char* ws = (char*)d_ws;
    size_t off = 0;
    auto alloc = [&](size_t bytes) { void* p = ws + off; off = (off + bytes + 255) & ~(size_t)255; return p; };

    int*   degd  = (int*)alloc(N_NODES * 4);
    int*   degs  = (int*)alloc(N_NODES * 4);
    int*   gcnt  = (int*)alloc(64);
    size_t zero_bytes = off;                         // zero prefix: degd, degs, gcnt
    int*   offf  = (int*)alloc(N_NODES * 4);
    int*   offb  = (int*)alloc(N_NODES * 4);
    int*   curf  = (int*)alloc(N_NODES * 4);
    int*   curb  = (int*)alloc(N_NODES * 4);
    float* normf = (float*)alloc(N_NODES * 4);
    float* normb = (float*)alloc(N_NODES * 4);
    int*   csrf  = (int*)alloc(N_EDGES * 4);
    int*   csrb  = (int*)alloc(N_EDGES * 4);
    unsigned short* featb = (unsigned short*)alloc((size_t)N_NODES * FEAT * 2);
    unsigned short* wall  = (unsigned short*)alloc((size_t)NCHUNK * 256 * FEAT * 2);   // 4 MB
    unsigned short* lwt   = (unsigned short*)alloc((size_t)FEAT * FEAT * 2);
    unsigned short* proj  = (unsigned short*)alloc((size_t)N_NODES * NCHUNK * FEAT * 2); // 164 MB
    (void)ws_size;

    hipMemsetAsync(d_ws, 0, zero_bytes, stream);

    // fused feat conversion + degree count
    {
        int n4 = N_NODES * FEAT / 4;
        k_prep<<<(n4 + 255) / 256, 256, 0, stream>>>((const float4*)feat, (ushort4*)featb, n4,
                                                     src, dst, degd, degs);
    }
    // all weight transposes
    {
        dim3 gw(4, 4, 33);
        k_wtall<<<gw, 256, 0, stream>>>(Wf, Wb, lw, wall, lwt);
    }
    // parallel segment allocation + norms, then CSR fill
    k_off<<<(N_NODES + 255) / 256, 256, 0, stream>>>(degd, degs, offf, offb, curf, curb,
                                                     normf, normb, gcnt);
    k_fill<<<(N_EDGES + 255) / 256, 256, 0, stream>>>(et, src, dst, curf, curb, csrf, csrb);

    // dense projection (y<157) + fused self loop (y>=157); gridDim.x stays 32
    {
        dim3 grid(NCHUNK, NTILES + SELFY);
        k_proj<<<grid, 256, 0, stream>>>(featb, wall, lwt, sbias, proj, out);
    }

    // pull-reduce both passes, RMW on out
    k_reduce<<<(N_NODES + 3) / 4, 256, 0, stream>>>(proj, csrf, csrb, offf, offb,
                                                    degd, degs, normf, normb,
                                                    fbias, bbias, out);
}

// Round 15
// 186.948 us; speedup vs baseline: 1.0121x; 1.0121x over previous
//
#include <hip/hip_runtime.h>
#include <hip/hip_bf16.h>
#include <stdint.h>

#define N_NODES 10000
#define N_EDGES 160000
#define FEAT    256
#define NRELS   16
#define BM      64          // row tile
#define NCHUNK  32          // 16 rels x {fwd,bwd}; proj row chunk = rd in [0,32)
#define KBYTES  512         // one A row = 256 bf16 = 512 B

typedef __attribute__((ext_vector_type(8))) short bf16x8;
typedef __attribute__((ext_vector_type(4))) float f32x4;

// native HW bf16 convert (RNE) -- compiler emits v_cvt (and packs pairs);
// manual bit-twiddled RNE was ~4 VALU ops and dominated the epilogue.
__device__ __forceinline__ unsigned short f2bf(float f) {
    __hip_bfloat16 h = __float2bfloat16(f);
    return *reinterpret_cast<unsigned short*>(&h);
}
__device__ __forceinline__ float bf2f(unsigned short u) {
    union { unsigned u; float f; } v; v.u = ((unsigned)u) << 16;
    return v.f;
}

// ---- fused prep: fp32 -> bf16 feat conversion + degree counting ----
__global__ __launch_bounds__(256) void k_prep(const float4* __restrict__ src4,
                                              ushort4* __restrict__ dst4, int n4,
                                              const int* __restrict__ src,
                                              const int* __restrict__ dst,
                                              int* degd, int* degs) {
    int i = blockIdx.x * 256 + threadIdx.x;
    if (i < n4) {
        float4 v = src4[i];
        ushort4 r;
        r.x = f2bf(v.x); r.y = f2bf(v.y); r.z = f2bf(v.z); r.w = f2bf(v.w);
        dst4[i] = r;
    }
    if (i < N_EDGES) {
        atomicAdd(&degd[dst[i]], 1);
        atomicAdd(&degs[src[i]], 1);
    }
}

// ---- all weight transposes: z<16 Wf -> rd 2z, z<32 Wb -> rd 2z+1, z==32 lw -> lwt ----
__global__ __launch_bounds__(256) void k_wtall(const float* __restrict__ Wf,
                                               const float* __restrict__ Wb,
                                               const float* __restrict__ lw,
                                               unsigned short* __restrict__ wall,
                                               unsigned short* __restrict__ lwt) {
    __shared__ float tile[64][65];
    int z = blockIdx.z;
    const float* w;
    unsigned short* o;
    if (z < 16)      { w = Wf + (size_t)z * 65536;        o = wall + (size_t)(z * 2) * 65536; }
    else if (z < 32) { w = Wb + (size_t)(z - 16) * 65536; o = wall + (size_t)((z - 16) * 2 + 1) * 65536; }
    else             { w = lw;                            o = lwt; }
    int i0 = blockIdx.x * 64, o0 = blockIdx.y * 64;
    int t = threadIdx.x;
    int c = t & 63, q = t >> 6;
#pragma unroll
    for (int it = 0; it < 16; it++) {
        int i = it * 4 + q;
        tile[i][c] = w[(size_t)(i0 + i) * 256 + o0 + c];
    }
    __syncthreads();
#pragma unroll
    for (int it = 0; it < 16; it++) {
        int oo = it * 4 + q;
        o[(size_t)(o0 + oo) * 256 + i0 + c] = f2bf(tile[c][oo]);
    }
}

// ---- parallel segment allocation: block-level scan + atomic base (order-free CSR) ----
__global__ __launch_bounds__(256) void k_off(const int* __restrict__ degd,
                                             const int* __restrict__ degs,
                                             int* offf, int* offb,
                                             int* curf, int* curb,
                                             float* normf, float* normb,
                                             int* gcnt) {
    __shared__ int sf[256], sb[256];
    __shared__ int basef, baseb;
    int t = threadIdx.x;
    int n = blockIdx.x * 256 + t;
    int df = (n < N_NODES) ? degd[n] : 0;
    int db = (n < N_NODES) ? degs[n] : 0;
    sf[t] = df; sb[t] = db;
    __syncthreads();
    for (int d = 1; d < 256; d <<= 1) {
        int vf = (t >= d) ? sf[t - d] : 0;
        int vb = (t >= d) ? sb[t - d] : 0;
        __syncthreads();
        sf[t] += vf; sb[t] += vb;
        __syncthreads();
    }
    if (t == 255) {
        basef = atomicAdd(&gcnt[0], sf[255]);
        baseb = atomicAdd(&gcnt[1], sb[255]);
    }
    __syncthreads();
    if (n < N_NODES) {
        int ef = basef + sf[t] - df;     // exclusive prefix + block base
        int eb = baseb + sb[t] - db;
        offf[n] = ef; offb[n] = eb;
        curf[n] = ef; curb[n] = eb;
        normf[n] = df > 0 ? 1.f / (float)df : 0.f;
        normb[n] = db > 0 ? 1.f / (float)db : 0.f;
    }
}

// ---- CSR fill: store proj chunk index (node*32 + et*2 + dir) ----
__global__ __launch_bounds__(256) void k_fill(const int* __restrict__ et,
                                              const int* __restrict__ src,
                                              const int* __restrict__ dst,
                                              int* curf, int* curb,
                                              int* csrf, int* csrb) {
    int e = blockIdx.x * 256 + threadIdx.x;
    if (e < N_EDGES) {
        int s = src[e], d = dst[e], r = et[e];
        csrf[atomicAdd(&curf[d], 1)] = s * NCHUNK + r * 2;       // fwd: feat[src] @ Wf
        csrb[atomicAdd(&curb[s], 1)] = d * NCHUNK + r * 2 + 1;   // bwd: feat[dst] @ Wb
    }
}

// ---- self loop: out = 2*(feat @ loop_weight) + self_bias  (overwrites out) ----
__global__ __launch_bounds__(256) void k_self(const unsigned short* __restrict__ featb,
                                              const unsigned short* __restrict__ lwt,
                                              const float* __restrict__ sbias,
                                              float* __restrict__ out) {
    int m0 = blockIdx.x * BM;
    int wave = threadIdx.x >> 6, lane = threadIdx.x & 63;
    int nb = wave * 64, lr = lane & 15, lg = lane >> 4;
    f32x4 acc[4][4] = {};
    for (int k0 = 0; k0 < FEAT; k0 += 32) {
        int kk = k0 + lg * 8;
        bf16x8 a[4], b[4];
        for (int mi = 0; mi < 4; mi++) {
            int row = m0 + mi * 16 + lr;
            if (row >= N_NODES) row = N_NODES - 1;
            a[mi] = *(const bf16x8*)(featb + row * FEAT + kk);
        }
        for (int ni = 0; ni < 4; ni++) {
            int col = nb + ni * 16 + lr;
            b[ni] = *(const bf16x8*)(lwt + col * FEAT + kk);
        }
        for (int mi = 0; mi < 4; mi++)
            for (int ni = 0; ni < 4; ni++)
                acc[mi][ni] = __builtin_amdgcn_mfma_f32_16x16x32_bf16(a[mi], b[ni], acc[mi][ni], 0, 0, 0);
    }
    for (int mi = 0; mi < 4; mi++) {
        for (int j = 0; j < 4; j++) {
            int row = m0 + mi * 16 + lg * 4 + j;
            if (row < N_NODES) {
                for (int ni = 0; ni < 4; ni++) {
                    int col = nb + ni * 16 + lr;
                    out[row * FEAT + col] = 2.0f * acc[mi][ni][j] + sbias[col];
                }
            }
        }
    }
}

// ---- dense projection: proj[n][rd][256] = feat @ W_rd  (exact r5/r13 structure) ----
__global__ __launch_bounds__(256) void k_proj(const unsigned short* __restrict__ featb,
                                              const unsigned short* __restrict__ wall,
                                              unsigned short* __restrict__ proj) {
    __shared__ __align__(16) char lds[BM * KBYTES];   // 32 KB: A tile, reused for out-stage
    int rd = blockIdx.x;
    int m0 = blockIdx.y * BM;
    int t = threadIdx.x;
    int wave = t >> 6, lane = t & 63;
    int nb = wave * 64, lr = lane & 15, lg = lane >> 4;
    const unsigned short* wr = wall + (size_t)rd * 256 * FEAT;

    // stage A tile [64][512B], swizzled: byte = row*512 + (kb ^ ((row&7)<<4))
    {
        int rl = t >> 5;                 // 0..7
        int kb = (t & 31) << 4;          // 0..496, 16B chunks
#pragma unroll
        for (int it = 0; it < 8; it++) {
            int row = it * 8 + rl;
            int gr = m0 + row; if (gr > N_NODES - 1) gr = N_NODES - 1;
            bf16x8 v = *(const bf16x8*)(featb + gr * FEAT + (kb >> 1));
            *(bf16x8*)(lds + row * KBYTES + (kb ^ ((row & 7) << 4))) = v;
        }
    }
    __syncthreads();

    f32x4 acc[4][4] = {};
#pragma unroll 2
    for (int k0 = 0; k0 < FEAT; k0 += 32) {
        int kb = (k0 + lg * 8) * 2;
        bf16x8 a[4], b[4];
        for (int ni = 0; ni < 4; ni++)
            b[ni] = *(const bf16x8*)(wr + (nb + ni * 16 + lr) * FEAT + k0 + lg * 8);
        for (int mi = 0; mi < 4; mi++) {
            int row = mi * 16 + lr;
            a[mi] = *(const bf16x8*)(lds + row * KBYTES + (kb ^ ((row & 7) << 4)));
        }
        for (int mi = 0; mi < 4; mi++)
            for (int ni = 0; ni < 4; ni++)
                acc[mi][ni] = __builtin_amdgcn_mfma_f32_16x16x32_bf16(a[mi], b[ni], acc[mi][ni], 0, 0, 0);
    }
    __syncthreads();

    // out-stage: bf16 results into LDS [64][256] linear (native cvt)
    for (int mi = 0; mi < 4; mi++) {
#pragma unroll
        for (int j = 0; j < 4; j++) {
            int row = mi * 16 + lg * 4 + j;
            for (int ni = 0; ni < 4; ni++)
                *(unsigned short*)(lds + row * KBYTES + (nb + ni * 16 + lr) * 2) =
                    f2bf(acc[mi][ni][j]);
        }
    }
    __syncthreads();

    // coalesced global write: 16B/lane, 512B bursts per row
    {
        int rl = t >> 5;
        int kb = (t & 31) << 4;
#pragma unroll
        for (int it = 0; it < 8; it++) {
            int row = it * 8 + rl;
            int gr = m0 + row;
            if (gr < N_NODES)
                *(bf16x8*)(proj + ((size_t)gr * NCHUNK + rd) * FEAT + (kb >> 1)) =
                    *(const bf16x8*)(lds + row * KBYTES + kb);
        }
    }
}

// ---- pull reduce: one wave per node, two 32-lane halves; RMW out (self already there) ----
__global__ __launch_bounds__(256) void k_reduce(const unsigned short* __restrict__ proj,
                                                const int* __restrict__ csrf,
                                                const int* __restrict__ csrb,
                                                const int* __restrict__ offf,
                                                const int* __restrict__ offb,
                                                const int* __restrict__ degd,
                                                const int* __restrict__ degs,
                                                const float* __restrict__ normf,
                                                const float* __restrict__ normb,
                                                const float* __restrict__ biasf,
                                                const float* __restrict__ biasb,
                                                float* __restrict__ out) {
    int node = blockIdx.x * 4 + (threadIdx.x >> 6);
    if (node >= N_NODES) return;
    int lane = threadIdx.x & 63;
    int half = lane >> 5;            // 0: even edges, 1: odd edges
    int li = lane & 31;              // 16B segment within the 512B row

    float af[8] = {0,0,0,0,0,0,0,0};
    float ab[8] = {0,0,0,0,0,0,0,0};

    int b0 = offf[node], dfc = degd[node];
    int b1 = b0 + dfc;
#pragma unroll 4
    for (int s = b0 + half; s < b1; s += 2) {
        int c = csrf[s];
        bf16x8 m = *(const bf16x8*)(proj + (size_t)c * FEAT + li * 8);
#pragma unroll
        for (int k = 0; k < 8; k++) af[k] += bf2f((unsigned short)m[k]);
    }
    int c0 = offb[node], dbc = degs[node];
    int c1 = c0 + dbc;
#pragma unroll 4
    for (int s = c0 + half; s < c1; s += 2) {
        int c = csrb[s];
        bf16x8 m = *(const bf16x8*)(proj + (size_t)c * FEAT + li * 8);
#pragma unroll
        for (int k = 0; k < 8; k++) ab[k] += bf2f((unsigned short)m[k]);
    }

    float nf = normf[node], nbv = normb[node];
    float v[8];
#pragma unroll
    for (int k = 0; k < 8; k++) v[k] = nf * af[k] + nbv * ab[k];
#pragma unroll
    for (int k = 0; k < 8; k++) v[k] += __shfl_xor(v[k], 32);   // combine halves

    // lane updates 4 floats at col = li*8 + half*4 (coalesced 1KB per wave)
    int col = li * 8 + half * 4;
    float4 bfv = *(const float4*)(biasf + col);
    float4 bbv = *(const float4*)(biasb + col);
    float fb = (dfc > 0) ? 1.f : 0.f;
    float bb = (dbc > 0) ? 1.f : 0.f;
    float4 o = *(float4*)(out + (size_t)node * FEAT + col);
    int k0 = half * 4;
    o.x += v[k0 + 0] + fb * bfv.x + bb * bbv.x;
    o.y += v[k0 + 1] + fb * bfv.y + bb * bbv.y;
    o.z += v[k0 + 2] + fb * bfv.z + bb * bbv.z;
    o.w += v[k0 + 3] + fb * bfv.w + bb * bbv.w;
    *(float4*)(out + (size_t)node * FEAT + col) = o;
}

extern "C" void kernel_launch(void* const* d_in, const int* in_sizes, int n_in,
                              void* d_out, int out_size, void* d_ws, size_t ws_size,
                              hipStream_t stream) {
    const float* feat  = (const float*)d_in[0];
    const float* Wf    = (const float*)d_in[1];
    const float* Wb    = (const float*)d_in[2];
    const float* lw    = (const float*)d_in[3];
    const float* fbias = (const float*)d_in[4];
    const float* bbias = (const float*)d_in[5];
    const float* sbias = (const float*)d_in[6];
    const int*   src   = (const int*)d_in[7];
    const int*   dst   = (const int*)d_in[8];
    const int*   et    = (const int*)d_in[9];
    float* out = (float*)d_out;

    char* ws = (char*)d_ws;
    size_t off = 0;
    auto alloc = [&](size_t bytes) { void* p = ws + off; off = (off + bytes + 255) & ~(size_t)255; return p; };

    int*   degd  = (int*)alloc(N_NODES * 4);
    int*   degs  = (int*)alloc(N_NODES * 4);
    int*   gcnt  = (int*)alloc(64);
    size_t zero_bytes = off;                         // zero prefix: degd, degs, gcnt
    int*   offf  = (int*)alloc(N_NODES * 4);
    int*   offb  = (int*)alloc(N_NODES * 4);
    int*   curf  = (int*)alloc(N_NODES * 4);
    int*   curb  = (int*)alloc(N_NODES * 4);
    float* normf = (float*)alloc(N_NODES * 4);
    float* normb = (float*)alloc(N_NODES * 4);
    int*   csrf  = (int*)alloc(N_EDGES * 4);
    int*   csrb  = (int*)alloc(N_EDGES * 4);
    unsigned short* featb = (unsigned short*)alloc((size_t)N_NODES * FEAT * 2);
    unsigned short* wall  = (unsigned short*)alloc((size_t)NCHUNK * 256 * FEAT * 2);   // 4 MB
    unsigned short* lwt   = (unsigned short*)alloc((size_t)FEAT * FEAT * 2);
    unsigned short* proj  = (unsigned short*)alloc((size_t)N_NODES * NCHUNK * FEAT * 2); // 164 MB
    (void)ws_size;

    hipMemsetAsync(d_ws, 0, zero_bytes, stream);

    // fused feat conversion + degree count
    {
        int n4 = N_NODES * FEAT / 4;
        k_prep<<<(n4 + 255) / 256, 256, 0, stream>>>((const float4*)feat, (ushort4*)featb, n4,
                                                     src, dst, degd, degs);
    }
    // all weight transposes
    {
        dim3 gw(4, 4, 33);
        k_wtall<<<gw, 256, 0, stream>>>(Wf, Wb, lw, wall, lwt);
    }
    // parallel segment allocation + norms, then CSR fill
    k_off<<<(N_NODES + 255) / 256, 256, 0, stream>>>(degd, degs, offf, offb, curf, curb,
                                                     normf, normb, gcnt);
    k_fill<<<(N_EDGES + 255) / 256, 256, 0, stream>>>(et, src, dst, curf, curb, csrf, csrb);

    // self loop writes out
    k_self<<<(N_NODES + BM - 1) / BM, 256, 0, stream>>>(featb, lwt, sbias, out);

    // dense projection for all 16 relations x {fwd,bwd}  (exact r5 config)
    {
        dim3 grid(NCHUNK, (N_NODES + BM - 1) / BM);
        k_proj<<<grid, 256, 0, stream>>>(featb, wall, proj);
    }

    // pull-reduce both passes, RMW on out
    k_reduce<<<(N_NODES + 3) / 4, 256, 0, stream>>>(proj, csrf, csrb, offf, offb,
                                                    degd, degs, normf, normb,
                                                    fbias, bbias, out);
}